// Round 5
// baseline (774.176 us; speedup 1.0000x reference)
//
#include <hip/hip_runtime.h>

#define N_  8
#define C_  32
#define H_  224
#define W_  224
#define TM_ 4
#define TA  32   // output tile extent along a (rows)
#define TB  32   // output tile extent along b (cols)

// Block = 256 threads handles one (c, 32x32 output tile) for ALL t (4) and n (8).
// Loop order: n OUTERMOST, t inner. For a fixed (block, n) the 4 t-warps sample
// nearly the same ~10 KB input window (warps = identity + 0.05*noise), so t=0
// fetches it and t=1..3 hit L1/L2. Geometry is recomputed per n (VALU has
// headroom); this keeps VGPRs low.
// NOTE (R4 post-mortem): nontemporal float4 stores were a 2.7x WRITE_SIZE /
// 5.5x FETCH_SIZE disaster on gfx950 — nt bypasses L2 write-allocate, which IS
// the write combiner; ECC HBM then RMWs partial granules. Plain stores here.
// Compute phase: lanes along a -> sample x consecutive per lane -> coalesced gathers.
// Write  phase: lanes along b -> coalesced float4 stores (via LDS transpose tile).
// Reference quirk preserved: hx = xs[a], hy = ys[b]; out channel = c*TM + t.
__global__ __launch_bounds__(256, 8) void persp_kernel(
    const float* __restrict__ inp,   // (N, C, H, W)
    const float* __restrict__ wt,    // (TM, C, 8)
    float* __restrict__ out)         // (N, C*TM, H, W)
{
    __shared__ float tile[TM_][TA][TB + 1];   // 16896 B -> 8 blocks/CU

    const int tid = threadIdx.x;
    const int c   = blockIdx.y;
    const int ta  = blockIdx.x / (W_ / TB);
    const int tb  = blockIdx.x % (W_ / TB);
    const int a0  = ta * TA;
    const int b0  = tb * TB;

    // compute-phase mapping: lane -> a, group -> b
    const int a_off = tid & 31;        // 0..31 along a (fast, per half-wave)
    const int bgrp  = tid >> 5;        // 0..7
    const int a     = a0 + a_off;

    const float step = 2.0f / 223.0f;  // linspace(-1,1,224) step
    const float hx   = -1.0f + (float)a * step;   // xs[a]

    // write-phase mapping: lane -> 4 consecutive b (float4), group -> a rows
    const int j4 = (tid & 7) * 4;      // 0,4,...,28 along b
    const int iw = tid >> 3;           // 0..31 along a

    const size_t plane   = (size_t)H_ * W_;
    const size_t istride = (size_t)C_ * plane;         // per-n input stride
    const size_t ostride = (size_t)(C_ * TM_) * plane; // per-n output stride

    // theta for all 4 t: uniform per block -> lands in SGPRs
    float th[TM_][8];
#pragma unroll
    for (int t = 0; t < TM_; ++t)
#pragma unroll
        for (int k = 0; k < 8; ++k)
            th[t][k] = wt[((size_t)t * C_ + c) * 8 + k];

    const float* ibase = inp + (size_t)c * plane;
    float* obase = out + ((size_t)c * TM_) * plane + (size_t)(a0 + iw) * W_ + (b0 + j4);

    for (int n = 0; n < N_; ++n) {
        const float* ib = ibase + (size_t)n * istride;

#pragma unroll
        for (int t = 0; t < TM_; ++t) {
#pragma unroll
            for (int p = 0; p < 4; ++p) {
                const int b = b0 + bgrp + 8 * p;
                const float hy = -1.0f + (float)b * step;  // ys[b]

                const float w0 = th[t][0] * hx + th[t][1] * hy + th[t][2];
                const float w1 = th[t][3] * hx + th[t][4] * hy + th[t][5];
                const float w2 = th[t][6] * hx + th[t][7] * hy + 1.0f;

                const float rw = 1.0f / w2;           // one divide, two muls
                const float xs = w0 * rw;
                const float ys = w1 * rw;

                const float x = 0.5f * ((xs + 1.0f) * 222.0f);
                const float y = 0.5f * ((ys + 1.0f) * 222.0f);

                int x0i = (int)floorf(x);
                int y0i = (int)floorf(y);
                int x1i = x0i + 1;
                int y1i = y0i + 1;
                x0i = min(max(x0i, 0), W_ - 1);
                x1i = min(max(x1i, 0), W_ - 1);
                y0i = min(max(y0i, 0), H_ - 1);
                y1i = min(max(y1i, 0), H_ - 1);

                const float x0f = (float)x0i, x1f = (float)x1i;
                const float y0f = (float)y0i, y1f = (float)y1i;

                const float wa = (x1f - x) * (y1f - y);
                const float wb = (x1f - x) * (y1f - y0f);
                const float wc = (x - x0f) * (y1f - y);
                const float wd = (x - x0f) * (y - y0f);

                const int iA = y0i * W_ + x0i;
                const int iB = y1i * W_ + x0i;
                const int iC = y0i * W_ + x1i;
                const int iD = y1i * W_ + x1i;

                const float Ia = ib[iA];
                const float Ib = ib[iB];
                const float Ic = ib[iC];
                const float Id = ib[iD];

                tile[t][a_off][bgrp + 8 * p] =
                    wa * Ia + wb * Ib + wc * Ic + wd * Id;
            }
        }
        __syncthreads();

        // coalesced float4 write-out: lanes along b (regular stores — L2 combines)
        float* on = obase + (size_t)n * ostride;
#pragma unroll
        for (int t = 0; t < TM_; ++t) {
            float4 v;
            v.x = tile[t][iw][j4 + 0];
            v.y = tile[t][iw][j4 + 1];
            v.z = tile[t][iw][j4 + 2];
            v.w = tile[t][iw][j4 + 3];
            *reinterpret_cast<float4*>(on + (size_t)t * plane) = v;
        }
        __syncthreads();
    }
}

extern "C" void kernel_launch(void* const* d_in, const int* in_sizes, int n_in,
                              void* d_out, int out_size, void* d_ws, size_t ws_size,
                              hipStream_t stream) {
    const float* inp = (const float*)d_in[0];   // (8,32,224,224) f32
    const float* wt  = (const float*)d_in[1];   // (4,32,8) f32
    float* out = (float*)d_out;                 // (8,128,224,224) f32

    dim3 grid((H_ / TA) * (W_ / TB), C_);       // 49 x 32 = 1568 blocks
    persp_kernel<<<grid, 256, 0, stream>>>(inp, wt, out);
}

// Round 6
// 327.234 us; speedup vs baseline: 2.3658x; 2.3658x over previous
//
#include <hip/hip_runtime.h>

#define N_  8
#define C_  32
#define H_  224
#define W_  224
#define TM_ 4
#define TA  32   // output tile extent along a (rows)
#define TB  32   // output tile extent along b (cols)
#define NC  4    // n processed per LDS pass

// R1-proven structure: t OUTER, n chunked (NC=4). Each t-pass streams the input
// once with full spatial utilization (FETCH = 4x input, flat); no reliance on
// temporal cache reuse (R4/R5 showed the n-outer "reuse" schedule death-spirals:
// 18x per-line refetch once block drift exceeds L2 residency).
// R6 change: all 64 gathers of an interval (4 planes x 4 samples x 4 taps) are
// issued into registers BEFORE any FMA/LDS consumption -> deep MLP per wave.
// __launch_bounds__(256,4) gives the allocator 128 VGPRs for the batch.
// Reference quirk preserved: hx = xs[a], hy = ys[b]; out channel = c*TM + t.
__global__ __launch_bounds__(256, 4) void persp_kernel(
    const float* __restrict__ inp,   // (N, C, H, W)
    const float* __restrict__ wt,    // (TM, C, 8)
    float* __restrict__ out)         // (N, C*TM, H, W)
{
    __shared__ float tile[NC][TA][TB + 1];   // 16896 B

    const int tid = threadIdx.x;
    const int c   = blockIdx.y;
    const int ta  = blockIdx.x / (W_ / TB);
    const int tb  = blockIdx.x % (W_ / TB);
    const int a0  = ta * TA;
    const int b0  = tb * TB;

    // compute-phase mapping: lane -> a, group -> b
    const int a_off = tid & 31;        // 0..31 along a (fast, per half-wave)
    const int bgrp  = tid >> 5;        // 0..7
    const int a     = a0 + a_off;

    const float step = 2.0f / 223.0f;  // linspace(-1,1,224) step
    const float hx   = -1.0f + (float)a * step;   // xs[a]

    // write-phase mapping: lane -> 4 consecutive b (float4), group -> a rows
    const int j4 = (tid & 7) * 4;      // 0,4,...,28 along b
    const int iw = tid >> 3;           // 0..31 along a

    const size_t plane   = (size_t)H_ * W_;
    const size_t istride = (size_t)C_ * plane;         // per-n input stride
    const size_t ostride = (size_t)(C_ * TM_) * plane; // per-n output stride

    const float* ibase = inp + (size_t)c * plane;

    for (int t = 0; t < TM_; ++t) {
        const float* th = wt + ((size_t)t * C_ + c) * 8;
        const float t0 = th[0], t1 = th[1], t2 = th[2], t3 = th[3];
        const float t4 = th[4], t5 = th[5], t6 = th[6], t7 = th[7];

        int   iA[4], iB[4], iC[4], iD[4];
        float wa[4], wb[4], wc[4], wd[4];

#pragma unroll
        for (int p = 0; p < 4; ++p) {
            const int b = b0 + bgrp + 8 * p;
            const float hy = -1.0f + (float)b * step;  // ys[b]

            const float w0 = t0 * hx + t1 * hy + t2;
            const float w1 = t3 * hx + t4 * hy + t5;
            const float w2 = t6 * hx + t7 * hy + 1.0f;

            const float xs = w0 / w2;
            const float ys = w1 / w2;

            const float x = 0.5f * ((xs + 1.0f) * 222.0f);
            const float y = 0.5f * ((ys + 1.0f) * 222.0f);

            int x0i = (int)floorf(x);
            int y0i = (int)floorf(y);
            int x1i = x0i + 1;
            int y1i = y0i + 1;
            x0i = min(max(x0i, 0), W_ - 1);
            x1i = min(max(x1i, 0), W_ - 1);
            y0i = min(max(y0i, 0), H_ - 1);
            y1i = min(max(y1i, 0), H_ - 1);

            const float x0f = (float)x0i, x1f = (float)x1i;
            const float y0f = (float)y0i, y1f = (float)y1i;

            wa[p] = (x1f - x) * (y1f - y);
            wb[p] = (x1f - x) * (y1f - y0f);
            wc[p] = (x - x0f) * (y1f - y);
            wd[p] = (x - x0f) * (y - y0f);

            iA[p] = y0i * W_ + x0i;
            iB[p] = y1i * W_ + x0i;
            iC[p] = y0i * W_ + x1i;
            iD[p] = y1i * W_ + x1i;
        }

#pragma unroll
        for (int nh = 0; nh < N_ / NC; ++nh) {
            // --- gather batch: issue ALL 64 loads before any consumption ---
            float va[NC][4], vb[NC][4], vc[NC][4], vd[NC][4];
#pragma unroll
            for (int nn = 0; nn < NC; ++nn) {
                const float* ib = ibase + (size_t)(nh * NC + nn) * istride;
#pragma unroll
                for (int p = 0; p < 4; ++p) {
                    va[nn][p] = ib[iA[p]];
                    vb[nn][p] = ib[iB[p]];
                    vc[nn][p] = ib[iC[p]];
                    vd[nn][p] = ib[iD[p]];
                }
            }
            // --- consume: FMA + LDS transpose tile ---
#pragma unroll
            for (int nn = 0; nn < NC; ++nn) {
#pragma unroll
                for (int p = 0; p < 4; ++p) {
                    tile[nn][a_off][bgrp + 8 * p] =
                        wa[p] * va[nn][p] + wb[p] * vb[nn][p] +
                        wc[p] * vc[nn][p] + wd[p] * vd[nn][p];
                }
            }
            __syncthreads();

            // coalesced float4 write-out: lanes along b
            float* ob = out + ((size_t)(c * TM_ + t)) * plane
                            + (size_t)(a0 + iw) * W_ + (b0 + j4);
#pragma unroll
            for (int nn = 0; nn < NC; ++nn) {
                const int n = nh * NC + nn;
                float4 v;
                v.x = tile[nn][iw][j4 + 0];
                v.y = tile[nn][iw][j4 + 1];
                v.z = tile[nn][iw][j4 + 2];
                v.w = tile[nn][iw][j4 + 3];
                *reinterpret_cast<float4*>(ob + (size_t)n * ostride) = v;
            }
            __syncthreads();
        }
    }
}

extern "C" void kernel_launch(void* const* d_in, const int* in_sizes, int n_in,
                              void* d_out, int out_size, void* d_ws, size_t ws_size,
                              hipStream_t stream) {
    const float* inp = (const float*)d_in[0];   // (8,32,224,224) f32
    const float* wt  = (const float*)d_in[1];   // (4,32,8) f32
    float* out = (float*)d_out;                 // (8,128,224,224) f32

    dim3 grid((H_ / TA) * (W_ / TB), C_);       // 49 x 32 = 1568 blocks
    persp_kernel<<<grid, 256, 0, stream>>>(inp, wt, out);
}